// Round 2
// baseline (9.799 us; speedup 1.0000x reference)
//
#include <hip/hip_runtime.h>
#include <math.h>

#define N_NODES 30
#define DD 768
#define SS 512
#define NPAIRS 435   // 30*29/2

__global__ __launch_bounds__(1024) void legal_pair_kernel(
    const float* __restrict__ bert,   // (B, 512, 768) f32
    const float* __restrict__ re_w,   // (1536,) f32
    const float* __restrict__ re_b,   // (1,) f32
    float* __restrict__ out)          // (B*435,) f32
{
    const int b    = blockIdx.x;
    const int tid  = threadIdx.x;
    const int lane = tid & 63;
    const int wave = tid >> 6;       // 0..15

    __shared__ float s_sm[N_NODES];
    __shared__ float t_sm[N_NODES];

    // weights: lane covers float4 slots lane + 64*it, it=0..2
    const float4* w1p = reinterpret_cast<const float4*>(re_w);
    const float4* w2p = reinterpret_cast<const float4*>(re_w + DD);

    const float* Eb = bert + (size_t)b * SS * DD;
    const int r0 = 2 * wave;          // rows 2w, 2w+1; wave 15 idle (r0=30)

    if (r0 < N_NODES) {
        const float4* row0 = reinterpret_cast<const float4*>(Eb + (size_t)r0 * DD);
        const float4* row1 = reinterpret_cast<const float4*>(Eb + (size_t)(r0 + 1) * DD);

        // hoist ALL loads (weights + both rows) before any FMA
        float4 w1v[3], w2v[3], e0[3], e1[3];
        #pragma unroll
        for (int it = 0; it < 3; ++it) {
            e0[it]  = row0[lane + 64 * it];
            e1[it]  = row1[lane + 64 * it];
            w1v[it] = w1p[lane + 64 * it];
            w2v[it] = w2p[lane + 64 * it];
        }

        float s0 = 0.f, t0 = 0.f, s1 = 0.f, t1 = 0.f;
        #pragma unroll
        for (int it = 0; it < 3; ++it) {
            s0 += e0[it].x * w1v[it].x + e0[it].y * w1v[it].y + e0[it].z * w1v[it].z + e0[it].w * w1v[it].w;
            t0 += e0[it].x * w2v[it].x + e0[it].y * w2v[it].y + e0[it].z * w2v[it].z + e0[it].w * w2v[it].w;
            s1 += e1[it].x * w1v[it].x + e1[it].y * w1v[it].y + e1[it].z * w1v[it].z + e1[it].w * w1v[it].w;
            t1 += e1[it].x * w2v[it].x + e1[it].y * w2v[it].y + e1[it].z * w2v[it].z + e1[it].w * w2v[it].w;
        }
        // 4 independent butterfly chains interleave across shfl latency
        #pragma unroll
        for (int off = 32; off > 0; off >>= 1) {
            s0 += __shfl_xor(s0, off, 64);
            t0 += __shfl_xor(t0, off, 64);
            s1 += __shfl_xor(s1, off, 64);
            t1 += __shfl_xor(t1, off, 64);
        }
        if (lane == 0) {
            s_sm[r0] = s0;  t_sm[r0] = t0;
            s_sm[r0 + 1] = s1;  t_sm[r0 + 1] = t1;
        }
    }
    __syncthreads();

    const float bias = re_b[0];
    if (tid < NPAIRS) {
        const int p = tid;
        int i = (int)((59.0f - sqrtf((float)(3481 - 8 * p))) * 0.5f);
        while (i * (59 - i) / 2 > p) --i;
        while ((i + 1) * (58 - i) / 2 <= p) ++i;
        const int j = p - i * (59 - i) / 2 + i + 1;
        const float x = s_sm[i] + t_sm[j] + bias;
        out[(size_t)b * NPAIRS + p] = 1.0f / (1.0f + expf(-x));
    }
}

extern "C" void kernel_launch(void* const* d_in, const int* in_sizes, int n_in,
                              void* d_out, int out_size, void* d_ws, size_t ws_size,
                              hipStream_t stream) {
    const float* bert = (const float*)d_in[0];
    const float* re_w = (const float*)d_in[1];
    const float* re_b = (const float*)d_in[2];
    float* out = (float*)d_out;

    const int B = in_sizes[0] / (SS * DD);   // 256
    legal_pair_kernel<<<B, 1024, 0, stream>>>(bert, re_w, re_b, out);
}

// Round 3
// 9.706 us; speedup vs baseline: 1.0096x; 1.0096x over previous
//
#include <hip/hip_runtime.h>
#include <math.h>

#define N_NODES 30
#define DD 768
#define SS 512
#define NPAIRS 435   // 30*29/2

// 15 waves, one row per wave — minimal critical path per block.
__global__ __launch_bounds__(960) void legal_pair_kernel(
    const float* __restrict__ bert,   // (B, 512, 768) f32
    const float* __restrict__ re_w,   // (1536,) f32
    const float* __restrict__ re_b,   // (1,) f32
    float* __restrict__ out)          // (B*435,) f32
{
    const int b    = blockIdx.x;
    const int tid  = threadIdx.x;
    const int lane = tid & 63;
    const int wave = tid >> 6;       // 0..14

    __shared__ float s_sm[N_NODES];
    __shared__ float t_sm[N_NODES];

    const float* Eb = bert + (size_t)b * SS * DD;
    const int r0 = 2 * wave;                 // even row for all waves
    const int r1 = (wave < 15) ? 0 : 0;      // (silence unused warn)
    (void)r1;

    // wave w handles rows: w<15 -> row w*2 is wrong for odd rows; instead:
    // 15 waves, 30 rows -> wave w does rows w and w+15 would serialize.
    // We want 1 row/wave for first 15 rows... but there are 30 rows.
    // Compromise: waves 0..14 each do 2 rows BUT fully independently
    // interleaved (same as R2). To get true 1-row/wave we use lane-split:
    // lanes 0..31 do row 2w (cols 0..767 via 24 float4 slots... )
    // Simplest true-minimal-depth: each wave does rows w and w+15 with all
    // loads hoisted and 4 interleaved reduce chains (identical depth to 1 row).
    const int ra = wave;        // 0..14
    const int rb = wave + 15;   // 15..29

    const float4* w1p = reinterpret_cast<const float4*>(re_w);
    const float4* w2p = reinterpret_cast<const float4*>(re_w + DD);
    const float4* rowA = reinterpret_cast<const float4*>(Eb + (size_t)ra * DD);
    const float4* rowB = reinterpret_cast<const float4*>(Eb + (size_t)rb * DD);

    float4 w1v[3], w2v[3], eA[3], eB[3];
    #pragma unroll
    for (int it = 0; it < 3; ++it) {
        eA[it]  = rowA[lane + 64 * it];
        eB[it]  = rowB[lane + 64 * it];
        w1v[it] = w1p[lane + 64 * it];
        w2v[it] = w2p[lane + 64 * it];
    }

    float sA = 0.f, tA = 0.f, sB = 0.f, tB = 0.f;
    #pragma unroll
    for (int it = 0; it < 3; ++it) {
        sA += eA[it].x * w1v[it].x + eA[it].y * w1v[it].y + eA[it].z * w1v[it].z + eA[it].w * w1v[it].w;
        tA += eA[it].x * w2v[it].x + eA[it].y * w2v[it].y + eA[it].z * w2v[it].z + eA[it].w * w2v[it].w;
        sB += eB[it].x * w1v[it].x + eB[it].y * w1v[it].y + eB[it].z * w1v[it].z + eB[it].w * w1v[it].w;
        tB += eB[it].x * w2v[it].x + eB[it].y * w2v[it].y + eB[it].z * w2v[it].z + eB[it].w * w2v[it].w;
    }
    #pragma unroll
    for (int off = 32; off > 0; off >>= 1) {
        sA += __shfl_xor(sA, off, 64);
        tA += __shfl_xor(tA, off, 64);
        sB += __shfl_xor(sB, off, 64);
        tB += __shfl_xor(tB, off, 64);
    }
    if (lane == 0) {
        s_sm[ra] = sA;  t_sm[ra] = tA;
        s_sm[rb] = sB;  t_sm[rb] = tB;
    }
    __syncthreads();

    const float bias = re_b[0];
    if (tid < NPAIRS) {
        const int p = tid;
        int i = (int)((59.0f - sqrtf((float)(3481 - 8 * p))) * 0.5f);
        while (i * (59 - i) / 2 > p) --i;
        while ((i + 1) * (58 - i) / 2 <= p) ++i;
        const int j = p - i * (59 - i) / 2 + i + 1;
        const float x = s_sm[i] + t_sm[j] + bias;
        out[(size_t)b * NPAIRS + p] = 1.0f / (1.0f + expf(-x));
    }
}

extern "C" void kernel_launch(void* const* d_in, const int* in_sizes, int n_in,
                              void* d_out, int out_size, void* d_ws, size_t ws_size,
                              hipStream_t stream) {
    const float* bert = (const float*)d_in[0];
    const float* re_w = (const float*)d_in[1];
    const float* re_b = (const float*)d_in[2];
    float* out = (float*)d_out;

    const int B = in_sizes[0] / (SS * DD);   // 256
    legal_pair_kernel<<<B, 960, 0, stream>>>(bert, re_w, re_b, out);
}